// Round 11
// baseline (389.932 us; speedup 1.0000x reference)
//
#include <hip/hip_runtime.h>

// MLPNodeLink: out[i,j] = relu(relu(relu([V1_i|V2_j]@W1+b1)@W2+b2)@W3+b3)
// h1[i,j] = relu(A[i] + B[j]), A=V1@W1[:128]+b1, B=V2@W1[128:]
// Round 11: persistent 256 blocks (1/CU), 8 tiles each. sA k-split into two
// 64KB halves; fill of next half-step interleaved into K-loop (1 write per
// odd s). bfr 4-slot distance-3 (B periodic in k: (sg+3)&31). Epilogue in 8
// rounds via 32KB buffer. LDS 160KB exactly. MFMA pipe = 8cy/CU per 32x32x16
// -> K floor 512cy/round; tiling mt=4/nt=2 keeps LDS-A 41us, L2-B 30us < 55us.

typedef short bf16x8 __attribute__((ext_vector_type(8)));
typedef float f32x16 __attribute__((ext_vector_type(16)));

#define NROW 512
#define FDIM 128
#define HDIM 512

__device__ __forceinline__ unsigned int pk2(float x, float y) {
  unsigned int r;
  asm("v_cvt_pk_bf16_f32 %0, %1, %2" : "=v"(r) : "v"(x), "v"(y));
  return r;
}

// ---- prep_ab: A[i][h] = V1[i]@W1[:128] + b1 ; B[j][h] = V2[j]@W1[128:] ----
__global__ __launch_bounds__(256) void prep_ab(
    const float* __restrict__ V1, const float* __restrict__ V2,
    const float* __restrict__ W1, const float* __restrict__ b1,
    float* __restrict__ Ap, float* __restrict__ Bp) {
  __shared__ float sv[4 * FDIM];
  const int b = blockIdx.x;
  const int t = threadIdx.x;
  const bool isB = b >= 128;
  const int r0 = (b & 127) * 4;
  const float* V = isB ? V2 : V1;
  const float* W = W1 + (isB ? FDIM * HDIM : 0);
  for (int idx = t; idx < 4 * FDIM; idx += 256) sv[idx] = V[r0 * FDIM + idx];
  __syncthreads();
  float s[4][2] = {};
  for (int k = 0; k < FDIM; ++k) {
    const float w0 = W[k * HDIM + t];
    const float w1 = W[k * HDIM + t + 256];
#pragma unroll
    for (int r = 0; r < 4; ++r) {
      const float v = sv[r * FDIM + k];
      s[r][0] += v * w0;
      s[r][1] += v * w1;
    }
  }
  float* O = isB ? Bp : Ap;
  const float bb0 = isB ? 0.f : b1[t];
  const float bb1 = isB ? 0.f : b1[t + 256];
#pragma unroll
  for (int r = 0; r < 4; ++r) {
    O[(r0 + r) * HDIM + t] = s[r][0] + bb0;
    O[(r0 + r) * HDIM + t + 256] = s[r][1] + bb1;
  }
}

// ---- prep_w2: bf16 W2^T as [kc=k/8 (64)][n (512)] 16B chunks ----
__global__ __launch_bounds__(256) void prep_w2(const float* __restrict__ W2,
                                               unsigned short* __restrict__ W2T) {
  const int o = blockIdx.x * 256 + threadIdx.x;  // 128*256 = 32768 chunks
  const int kc = o >> 9;
  const int n = o & 511;
  unsigned int u[4];
#pragma unroll
  for (int e2 = 0; e2 < 4; ++e2)
    u[e2] = pk2(W2[(kc * 8 + 2 * e2) * HDIM + n], W2[(kc * 8 + 2 * e2 + 1) * HDIM + n]);
  *(uint4*)(W2T + (size_t)o * 8) = make_uint4(u[0], u[1], u[2], u[3]);
}

// fill one 16-row group (w) of a 64KB sA half. bpn = Bp + j0n*HDIM + khn,
// apn preloaded 8 floats of Ap row for khn. row = w*16 + rsub.
__device__ __forceinline__ void fill_w(char* sAbuf, int w, int rsub, int c32,
                                       const float4& a0, const float4& a1,
                                       const float* bpn) {
  const int row = w * 16 + rsub;
  const float* bp = bpn + (size_t)row * HDIM;
  const float4 g0 = *(const float4*)(bp);
  const float4 g1 = *(const float4*)(bp + 4);
  const uint4 v = make_uint4(
      pk2(fmaxf(a0.x + g0.x, 0.f), fmaxf(a0.y + g0.y, 0.f)),
      pk2(fmaxf(a0.z + g0.z, 0.f), fmaxf(a0.w + g0.w, 0.f)),
      pk2(fmaxf(a1.x + g1.x, 0.f), fmaxf(a1.y + g1.y, 0.f)),
      pk2(fmaxf(a1.z + g1.z, 0.f), fmaxf(a1.w + g1.w, 0.f)));
  *(uint4*)(sAbuf + row * 512 + ((c32 ^ rsub) << 4)) = v;
}

// ---- main: persistent; 256 blocks, 8 tiles each (tile = bid*8+t, 128 rows).
// 8 waves; wave = 128x64 (4mt x 2nt of 32x32). sA halves 64KB @0/@65536,
// epilogue buffer 32KB @131072.
__global__ __launch_bounds__(512, 2) void mlp_main(
    const float* __restrict__ Ap, const float* __restrict__ Bp,
    const unsigned short* __restrict__ W2T, const float* __restrict__ b2,
    const float* __restrict__ W3, const float* __restrict__ b3,
    float* __restrict__ out) {
  extern __shared__ char smem[];
  char* epi = smem + 131072;  // [8 rpi][256 slots][16B]

  const int tid = threadIdx.x;
  const int wave = tid >> 6;
  const int lane = tid & 63;
  const int cl = lane & 31;
  const int hi = lane >> 5;
  const int r15 = lane & 15;
  const int c32 = tid & 31;   // fill chunk
  const int rsub = tid >> 5;  // fill row-sub 0..15
  const int bid = blockIdx.x;

  // epilogue weights (wave's 64-col range, nt in {0,1})
  float w30[2], w31[2], bb[2];
#pragma unroll
  for (int nt = 0; nt < 2; ++nt) {
    const int n = (wave << 6) + (nt << 5) + cl;
    w30[nt] = W3[2 * n];
    w31[nt] = W3[2 * n + 1];
    bb[nt] = b2[n];
  }
  const float bb3_0 = b3[0], bb3_1 = b3[1];

  const char* bbase = (const char*)W2T + (((wave << 6) + cl) << 4) + (hi << 13);

  f32x16 acc[4][2];
#pragma unroll
  for (int mt = 0; mt < 4; ++mt)
#pragma unroll
    for (int nt = 0; nt < 2; ++nt)
#pragma unroll
      for (int q = 0; q < 16; ++q) acc[mt][nt][q] = 0.f;

  bf16x8 af[2][4], bfr[4][2];

  // bfr prologue: sg = 0,1,2
#pragma unroll
  for (int q = 0; q < 3; ++q) {
    const char* bp = bbase + ((size_t)q << 14);
    bfr[q][0] = *(const bf16x8*)(bp);
    bfr[q][1] = *(const bf16x8*)(bp + (1 << 9));
  }

  // prologue fill: (tile bid*8, h0) -> sA0
  {
    const int m00 = bid * 1024;  // (bid*8)*128
    const int i0 = m00 >> 9;
    const int j00 = m00 & 511;  // == 0
    const int kh = c32 * 8;
    const float4 a0 = *(const float4*)(Ap + i0 * HDIM + kh);
    const float4 a1 = *(const float4*)(Ap + i0 * HDIM + kh + 4);
    const float* bpn = Bp + (size_t)j00 * HDIM + kh;
#pragma unroll
    for (int w = 0; w < 8; ++w) fill_w(smem, w, rsub, c32, a0, a1, bpn);
  }
  __syncthreads();

  for (int t = 0; t < 8; ++t) {
    const int tl = bid * 8 + t;
    const int m0 = tl * 128;
#pragma unroll
    for (int h = 0; h < 2; ++h) {
      char* sAbuf = smem + h * 65536;
      char* sAnext = smem + (h ^ 1) * 65536;
      // next half-step params (OOB-safe past last tile: lands in Bp region)
      const int tln = (h == 0) ? tl : tl + 1;
      const int hn = h ^ 1;
      const int m0n = tln * 128;
      const int in_ = m0n >> 9;
      const int j0n = m0n & 511;
      const int khn = hn * 256 + c32 * 8;
      const float4 a0n = *(const float4*)(Ap + (size_t)in_ * HDIM + khn);
      const float4 a1n = *(const float4*)(Ap + (size_t)in_ * HDIM + khn + 4);
      const float* bpn = Bp + (size_t)j0n * HDIM + khn;

      const char* alane = sAbuf + cl * 512;
      // af s=0 prologue
      {
        const int off = (hi ^ r15) << 4;
#pragma unroll
        for (int mt = 0; mt < 4; ++mt)
          af[0][mt] = *(const bf16x8*)(alane + mt * 16384 + off);
      }
#pragma unroll
      for (int s = 0; s < 16; ++s) {
        const int sg = h * 16 + s;
        // bfr prefetch distance 3 (periodic in k)
        {
          const int pg = (sg + 3) & 31;
          const char* bp = bbase + ((size_t)pg << 14);
          bfr[pg & 3][0] = *(const bf16x8*)(bp);
          bfr[pg & 3][1] = *(const bf16x8*)(bp + (1 << 9));
        }
        // af prefetch s+1
        if (s < 15) {
          const int off = ((((s + 1) << 1) | hi) ^ r15) << 4;
#pragma unroll
          for (int mt = 0; mt < 4; ++mt)
            af[(s + 1) & 1][mt] = *(const bf16x8*)(alane + mt * 16384 + off);
        }
        // interleaved fill of next half-step (1 write per odd s)
        if (s & 1) fill_w(sAnext, s >> 1, rsub, c32, a0n, a1n, bpn);
        // MFMA cluster
#pragma unroll
        for (int nt = 0; nt < 2; ++nt)
#pragma unroll
          for (int mt = 0; mt < 4; ++mt)
            acc[mt][nt] = __builtin_amdgcn_mfma_f32_32x32x16_bf16(
                af[s & 1][mt], bfr[sg & 3][nt], acc[mt][nt], 0, 0, 0);
      }
      __syncthreads();
    }

    // ---- epilogue: 8 rounds (mt x g), 32KB buffer ----
#pragma unroll
    for (int mt = 0; mt < 4; ++mt) {
#pragma unroll
      for (int g = 0; g < 2; ++g) {
#pragma unroll
        for (int rr = 0; rr < 4; ++rr) {
          const int ra = 8 * g + 2 * rr;
          const float h0a = fmaxf(acc[mt][0][ra] + bb[0], 0.f);
          const float h1a = fmaxf(acc[mt][1][ra] + bb[1], 0.f);
          const float h0b = fmaxf(acc[mt][0][ra + 1] + bb[0], 0.f);
          const float h1b = fmaxf(acc[mt][1][ra + 1] + bb[1], 0.f);
          const float4 v =
              make_float4(h0a * w30[0] + h1a * w30[1], h0a * w31[0] + h1a * w31[1],
                          h0b * w30[0] + h1b * w30[1], h0b * w31[0] + h1b * w31[1]);
          const int rpi_l = (((ra & 7) & 3) + 8 * ((ra & 7) >> 2) + 4 * hi) >> 1;
          *(float4*)(epi + rpi_l * 4096 + (((wave << 5) + cl) << 4)) = v;
        }
        __syncthreads();
        if (tid < 128) {
          const int rpi_l = tid >> 4;
          const int sub = tid & 15;
          float4 s = make_float4(0.f, 0.f, 0.f, 0.f);
#pragma unroll
          for (int k = 0; k < 16; ++k) {
            const float4 v = *(const float4*)(epi + rpi_l * 4096 + ((sub + (k << 4)) << 4));
            s.x += v.x; s.y += v.y; s.z += v.z; s.w += v.w;
          }
#pragma unroll
          for (int d = 1; d < 16; d <<= 1) {
            s.x += __shfl_xor(s.x, d, 64);
            s.y += __shfl_xor(s.y, d, 64);
            s.z += __shfl_xor(s.z, d, 64);
            s.w += __shfl_xor(s.w, d, 64);
          }
          if (sub == 0) {
            const int rg = m0 + (mt << 5) + (g << 4) + (rpi_l << 1);
            *(float4*)(out + rg * 2) =
                make_float4(fmaxf(s.x + bb3_0, 0.f), fmaxf(s.y + bb3_1, 0.f),
                            fmaxf(s.z + bb3_0, 0.f), fmaxf(s.w + bb3_1, 0.f));
          }
        }
        __syncthreads();
      }
      // consume done: zero acc for next tile
#pragma unroll
      for (int nt = 0; nt < 2; ++nt)
#pragma unroll
        for (int q = 0; q < 16; ++q) acc[mt][nt][q] = 0.f;
    }
  }
}

extern "C" void kernel_launch(void* const* d_in, const int* in_sizes, int n_in,
                              void* d_out, int out_size, void* d_ws, size_t ws_size,
                              hipStream_t stream) {
  const float* V1 = (const float*)d_in[0];
  const float* V2 = (const float*)d_in[1];
  const float* W1 = (const float*)d_in[2];
  const float* b1 = (const float*)d_in[3];
  const float* W2 = (const float*)d_in[4];
  const float* b2 = (const float*)d_in[5];
  const float* W3 = (const float*)d_in[6];
  const float* b3 = (const float*)d_in[7];

  // ws layout: Ap (1MB f32) | Bp (1MB f32) | W2T (512KB bf16 tiled)
  float* Ap = (float*)d_ws;
  float* Bp = Ap + NROW * HDIM;
  unsigned short* W2T = (unsigned short*)(Bp + NROW * HDIM);

  const int smem_bytes = 163840;  // 2x64KB sA halves + 32KB epilogue
  (void)hipFuncSetAttribute((const void*)mlp_main,
                            hipFuncAttributeMaxDynamicSharedMemorySize, smem_bytes);

  prep_ab<<<256, 256, 0, stream>>>(V1, V2, W1, b1, Ap, Bp);
  prep_w2<<<128, 256, 0, stream>>>(W2, W2T);
  mlp_main<<<256, 512, smem_bytes, stream>>>(Ap, Bp, W2T, b2, W3, b3, (float*)d_out);
}

// Round 12
// 324.682 us; speedup vs baseline: 1.2010x; 1.2010x over previous
//
#include <hip/hip_runtime.h>

// MLPNodeLink: out[i,j] = relu(relu(relu([V1_i|V2_j]@W1+b1)@W2+b2)@W3+b3)
// h1[i,j] = relu(A[i] + B[j]), A=V1@W1[:128]+b1, B=V2@W1[128:]
// Round 12: r11's persistent/interleaved-fill plan, spill-proofed.
// - fill split load(even s)/pack+write(odd s), sched_barrier(0) per round
//   pins loads -> max 1 fill group (8 VGPR) in flight (r11 spilled ~64).
// - bfr 4-slot distance-3, k-periodic (wrap-safe across tiles).
// - two 64KB sA k-halves; epilogue reuses consumed half; 5-bit XOR swizzle.

typedef short bf16x8 __attribute__((ext_vector_type(8)));
typedef float f32x16 __attribute__((ext_vector_type(16)));

#define NROW 512
#define FDIM 128
#define HDIM 512

__device__ __forceinline__ unsigned int pk2(float x, float y) {
  unsigned int r;
  asm("v_cvt_pk_bf16_f32 %0, %1, %2" : "=v"(r) : "v"(x), "v"(y));
  return r;
}

// ---- prep_ab: A[i][h] = V1[i]@W1[:128] + b1 ; B[j][h] = V2[j]@W1[128:] ----
__global__ __launch_bounds__(256) void prep_ab(
    const float* __restrict__ V1, const float* __restrict__ V2,
    const float* __restrict__ W1, const float* __restrict__ b1,
    float* __restrict__ Ap, float* __restrict__ Bp) {
  __shared__ float sv[4 * FDIM];
  const int b = blockIdx.x;
  const int t = threadIdx.x;
  const bool isB = b >= 128;
  const int r0 = (b & 127) * 4;
  const float* V = isB ? V2 : V1;
  const float* W = W1 + (isB ? FDIM * HDIM : 0);
  for (int idx = t; idx < 4 * FDIM; idx += 256) sv[idx] = V[r0 * FDIM + idx];
  __syncthreads();
  float s[4][2] = {};
  for (int k = 0; k < FDIM; ++k) {
    const float w0 = W[k * HDIM + t];
    const float w1 = W[k * HDIM + t + 256];
#pragma unroll
    for (int r = 0; r < 4; ++r) {
      const float v = sv[r * FDIM + k];
      s[r][0] += v * w0;
      s[r][1] += v * w1;
    }
  }
  float* O = isB ? Bp : Ap;
  const float bb0 = isB ? 0.f : b1[t];
  const float bb1 = isB ? 0.f : b1[t + 256];
#pragma unroll
  for (int r = 0; r < 4; ++r) {
    O[(r0 + r) * HDIM + t] = s[r][0] + bb0;
    O[(r0 + r) * HDIM + t + 256] = s[r][1] + bb1;
  }
}

// ---- prep_w2: bf16 W2^T as [kc=k/8 (64)][n (512)] 16B chunks ----
__global__ __launch_bounds__(256) void prep_w2(const float* __restrict__ W2,
                                               unsigned short* __restrict__ W2T) {
  const int o = blockIdx.x * 256 + threadIdx.x;  // 128*256 = 32768 chunks
  const int kc = o >> 9;
  const int n = o & 511;
  unsigned int u[4];
#pragma unroll
  for (int e2 = 0; e2 < 4; ++e2)
    u[e2] = pk2(W2[(kc * 8 + 2 * e2) * HDIM + n], W2[(kc * 8 + 2 * e2 + 1) * HDIM + n]);
  *(uint4*)(W2T + (size_t)o * 8) = make_uint4(u[0], u[1], u[2], u[3]);
}

// ---- main: persistent; 256 blocks x 8 tiles (tile = 128 rows x 512 cols).
// 8 waves; wave = 128x64 (4mt x 2nt of 32x32). K split in two 256-halves;
// sA halves 64KB @0/@65536. During half h's 16 rounds, the other half is
// filled for (h==0 ? same tile k-hi : next tile k-lo).
__global__ __launch_bounds__(512, 2) void mlp_main(
    const float* __restrict__ Ap, const float* __restrict__ Bp,
    const unsigned short* __restrict__ W2T, const float* __restrict__ b2,
    const float* __restrict__ W3, const float* __restrict__ b3,
    float* __restrict__ out) {
  extern __shared__ char smem[];

  const int tid = threadIdx.x;
  const int wave = tid >> 6;
  const int lane = tid & 63;
  const int cl = lane & 31;
  const int hi = lane >> 5;
  const int c32 = tid & 31;   // fill k-octet within half
  const int rsub = tid >> 5;  // fill row-sub 0..15
  const int bid = blockIdx.x;

  // epilogue weights
  float w30[2], w31[2], bb[2];
#pragma unroll
  for (int nt = 0; nt < 2; ++nt) {
    const int n = (wave << 6) + (nt << 5) + cl;
    w30[nt] = W3[2 * n];
    w31[nt] = W3[2 * n + 1];
    bb[nt] = b2[n];
  }
  const float bb3_0 = b3[0], bb3_1 = b3[1];

  const char* bbase = (const char*)W2T + (((wave << 6) + cl) << 4) + (hi << 13);

  f32x16 acc[4][2];
#pragma unroll
  for (int mt = 0; mt < 4; ++mt)
#pragma unroll
    for (int nt = 0; nt < 2; ++nt)
#pragma unroll
      for (int q = 0; q < 16; ++q) acc[mt][nt][q] = 0.f;

  bf16x8 af[2][4], bfr[4][2];

  // bfr prologue: k-groups 0,1,2 -> slots 0,1,2
#pragma unroll
  for (int q = 0; q < 3; ++q) {
    const char* bp = bbase + ((size_t)q << 14);
    bfr[q][0] = *(const bf16x8*)(bp);
    bfr[q][1] = *(const bf16x8*)(bp + (1 << 9));
  }

  // prologue fill: tile bid*8, k-half 0 -> halfA (serial)
  {
    const int i0 = bid * 2;  // (bid*1024)>>9
    const float4 a0 = *(const float4*)(Ap + (size_t)i0 * HDIM + c32 * 8);
    const float4 a1 = *(const float4*)(Ap + (size_t)i0 * HDIM + c32 * 8 + 4);
    const float* bpn = Bp + (size_t)rsub * HDIM + c32 * 8;  // j00 = 0
#pragma unroll
    for (int w = 0; w < 8; ++w) {
      const int row = w * 16 + rsub;
      const float4 g0 = *(const float4*)(bpn + (size_t)w * 8192);
      const float4 g1 = *(const float4*)(bpn + (size_t)w * 8192 + 4);
      const uint4 v = make_uint4(
          pk2(fmaxf(a0.x + g0.x, 0.f), fmaxf(a0.y + g0.y, 0.f)),
          pk2(fmaxf(a0.z + g0.z, 0.f), fmaxf(a0.w + g0.w, 0.f)),
          pk2(fmaxf(a1.x + g1.x, 0.f), fmaxf(a1.y + g1.y, 0.f)),
          pk2(fmaxf(a1.z + g1.z, 0.f), fmaxf(a1.w + g1.w, 0.f)));
      *(uint4*)(smem + row * 512 + ((c32 ^ (row & 31)) << 4)) = v;
    }
  }
  __syncthreads();

#pragma unroll 1
  for (int t = 0; t < 8; ++t) {
    const int tl = bid * 8 + t;
    const int m0 = tl * 128;
#pragma unroll
    for (int h = 0; h < 2; ++h) {
      char* sAbuf = smem + h * 65536;
      char* sAnext = smem + (h ^ 1) * 65536;
      // next-fill target: h==0 -> same tile k-half1; h==1 -> next tile k-half0
      const int tln = (h == 0) ? tl : tl + 1;
      const int khn = (h ^ 1) * 256;
      const int in_ = (tln * 128) >> 9;   // OOB-safe at end: lands in Bp
      const int j0n = (tln * 128) & 511;
      const float4 a0n = *(const float4*)(Ap + (size_t)in_ * HDIM + khn + c32 * 8);
      const float4 a1n = *(const float4*)(Ap + (size_t)in_ * HDIM + khn + c32 * 8 + 4);
      const float* bpn = Bp + (size_t)(j0n + rsub) * HDIM + khn + c32 * 8;

      const char* alane = sAbuf + cl * 512;
      // af s=0 prologue
      {
        const int off = (hi ^ cl) << 4;
#pragma unroll
        for (int mt = 0; mt < 4; ++mt)
          af[0][mt] = *(const bf16x8*)(alane + mt * 16384 + off);
      }
      float4 gg0, gg1;
#pragma unroll
      for (int s = 0; s < 16; ++s) {
        __builtin_amdgcn_sched_barrier(0);
        const int sg = h * 16 + s;
        // bfr prefetch distance 3 (k-periodic, wrap-safe)
        {
          const int pg = (sg + 3) & 31;
          const char* bp = bbase + ((size_t)pg << 14);
          bfr[pg & 3][0] = *(const bf16x8*)(bp);
          bfr[pg & 3][1] = *(const bf16x8*)(bp + (1 << 9));
        }
        // af prefetch s+1
        if (s < 15) {
          const int off = ((((s + 1) << 1) | hi) ^ cl) << 4;
#pragma unroll
          for (int mt = 0; mt < 4; ++mt)
            af[(s + 1) & 1][mt] = *(const bf16x8*)(alane + mt * 16384 + off);
        }
        // interleaved fill: even s = issue loads; odd s = pack + LDS write
        if ((s & 1) == 0) {
          const int w = s >> 1;
          gg0 = *(const float4*)(bpn + (size_t)w * 8192);
          gg1 = *(const float4*)(bpn + (size_t)w * 8192 + 4);
        } else {
          const int w = s >> 1;
          const int row = w * 16 + rsub;
          const uint4 v = make_uint4(
              pk2(fmaxf(a0n.x + gg0.x, 0.f), fmaxf(a0n.y + gg0.y, 0.f)),
              pk2(fmaxf(a0n.z + gg0.z, 0.f), fmaxf(a0n.w + gg0.w, 0.f)),
              pk2(fmaxf(a1n.x + gg1.x, 0.f), fmaxf(a1n.y + gg1.y, 0.f)),
              pk2(fmaxf(a1n.z + gg1.z, 0.f), fmaxf(a1n.w + gg1.w, 0.f)));
          *(uint4*)(sAnext + row * 512 + ((c32 ^ (row & 31)) << 4)) = v;
        }
        // MFMA cluster
        __builtin_amdgcn_s_setprio(1);
#pragma unroll
        for (int nt = 0; nt < 2; ++nt)
#pragma unroll
          for (int mt = 0; mt < 4; ++mt)
            acc[mt][nt] = __builtin_amdgcn_mfma_f32_32x32x16_bf16(
                af[s & 1][mt], bfr[sg & 3][nt], acc[mt][nt], 0, 0, 0);
        __builtin_amdgcn_s_setprio(0);
      }
      __syncthreads();
    }

    // ---- epilogue: 4 mt rounds; buffer = just-consumed halfB (64KB) ----
    char* ebuf = smem + 65536;
#pragma unroll
    for (int mt = 0; mt < 4; ++mt) {
#pragma unroll
      for (int rp = 0; rp < 8; ++rp) {
        const int ra = 2 * rp;
        const float h0a = fmaxf(acc[mt][0][ra] + bb[0], 0.f);
        const float h1a = fmaxf(acc[mt][1][ra] + bb[1], 0.f);
        const float h0b = fmaxf(acc[mt][0][ra + 1] + bb[0], 0.f);
        const float h1b = fmaxf(acc[mt][1][ra + 1] + bb[1], 0.f);
        const float4 v =
            make_float4(h0a * w30[0] + h1a * w30[1], h0a * w31[0] + h1a * w31[1],
                        h0b * w30[0] + h1b * w30[1], h0b * w31[0] + h1b * w31[1]);
        const int rpi = (((ra & 3) + 8 * (ra >> 2) + 4 * hi)) >> 1;
        *(float4*)(ebuf + rpi * 4096 + (((wave << 5) + cl) << 4)) = v;
      }
      __syncthreads();
      {
        const int rpi = tid >> 5;  // 0..15
        const int sub = tid & 31;  // 32 threads per rowpair
        float4 s = make_float4(0.f, 0.f, 0.f, 0.f);
#pragma unroll
        for (int k = 0; k < 8; ++k) {
          const float4 v = *(const float4*)(ebuf + rpi * 4096 + ((sub + (k << 5)) << 4));
          s.x += v.x; s.y += v.y; s.z += v.z; s.w += v.w;
        }
#pragma unroll
        for (int d = 1; d < 32; d <<= 1) {
          s.x += __shfl_xor(s.x, d, 64);
          s.y += __shfl_xor(s.y, d, 64);
          s.z += __shfl_xor(s.z, d, 64);
          s.w += __shfl_xor(s.w, d, 64);
        }
        if (sub == 0) {
          const int rg = m0 + (mt << 5) + (rpi << 1);
          *(float4*)(out + rg * 2) =
              make_float4(fmaxf(s.x + bb3_0, 0.f), fmaxf(s.y + bb3_1, 0.f),
                          fmaxf(s.z + bb3_0, 0.f), fmaxf(s.w + bb3_1, 0.f));
        }
      }
      __syncthreads();
      // acc consumed: zero for next tile
#pragma unroll
      for (int nt = 0; nt < 2; ++nt)
#pragma unroll
        for (int q = 0; q < 16; ++q) acc[mt][nt][q] = 0.f;
    }
  }
}

extern "C" void kernel_launch(void* const* d_in, const int* in_sizes, int n_in,
                              void* d_out, int out_size, void* d_ws, size_t ws_size,
                              hipStream_t stream) {
  const float* V1 = (const float*)d_in[0];
  const float* V2 = (const float*)d_in[1];
  const float* W1 = (const float*)d_in[2];
  const float* b1 = (const float*)d_in[3];
  const float* W2 = (const float*)d_in[4];
  const float* b2 = (const float*)d_in[5];
  const float* W3 = (const float*)d_in[6];
  const float* b3 = (const float*)d_in[7];

  // ws layout: Ap (1MB f32) | Bp (1MB f32) | W2T (512KB bf16 tiled)
  float* Ap = (float*)d_ws;
  float* Bp = Ap + NROW * HDIM;
  unsigned short* W2T = (unsigned short*)(Bp + NROW * HDIM);

  const int smem_bytes = 131072;  // two 64KB sA halves (epi reuses one)
  (void)hipFuncSetAttribute((const void*)mlp_main,
                            hipFuncAttributeMaxDynamicSharedMemorySize, smem_bytes);

  prep_ab<<<256, 256, 0, stream>>>(V1, V2, W1, b1, Ap, Bp);
  prep_w2<<<128, 256, 0, stream>>>(W2, W2T);
  mlp_main<<<256, 512, smem_bytes, stream>>>(Ap, Bp, W2T, b2, W3, b3, (float*)d_out);
}

// Round 13
// 157.897 us; speedup vs baseline: 2.4695x; 2.0563x over previous
//
#include <hip/hip_runtime.h>

// MLPNodeLink: out[i,j] = relu(relu(relu([V1_i|V2_j]@W1+b1)@W2+b2)@W3+b3)
// h1[i,j] = relu(A[i] + B[j]), A=V1@W1[:128]+b1, B=V2@W1[128:]
// Round 13: r9 green anchor + bfr prefetch 3-slot distance-2 (L2 latency
// cover ~500cy vs r9's ~260cy 1-deep). Everything else identical to r9:
// BM=64, 8 waves, wave=64x64 (2mt x 2nt of 32x32), 4 waves/SIMD,
// 2 blocks/CU (fill/epilogue overlap across blocks), 64KB sA, VGPR ~124.

typedef short bf16x8 __attribute__((ext_vector_type(8)));
typedef float f32x16 __attribute__((ext_vector_type(16)));

#define NROW 512
#define FDIM 128
#define HDIM 512

__device__ __forceinline__ unsigned int pk2(float x, float y) {
  unsigned int r;
  asm("v_cvt_pk_bf16_f32 %0, %1, %2" : "=v"(r) : "v"(x), "v"(y));
  return r;
}

// ---- prep_ab: A[i][h] = V1[i]@W1[:128] + b1 ; B[j][h] = V2[j]@W1[128:] ----
__global__ __launch_bounds__(256) void prep_ab(
    const float* __restrict__ V1, const float* __restrict__ V2,
    const float* __restrict__ W1, const float* __restrict__ b1,
    float* __restrict__ Ap, float* __restrict__ Bp) {
  __shared__ float sv[4 * FDIM];
  const int b = blockIdx.x;
  const int t = threadIdx.x;
  const bool isB = b >= 128;
  const int r0 = (b & 127) * 4;
  const float* V = isB ? V2 : V1;
  const float* W = W1 + (isB ? FDIM * HDIM : 0);
  for (int idx = t; idx < 4 * FDIM; idx += 256) sv[idx] = V[r0 * FDIM + idx];
  __syncthreads();
  float s[4][2] = {};
  for (int k = 0; k < FDIM; ++k) {
    const float w0 = W[k * HDIM + t];
    const float w1 = W[k * HDIM + t + 256];
#pragma unroll
    for (int r = 0; r < 4; ++r) {
      const float v = sv[r * FDIM + k];
      s[r][0] += v * w0;
      s[r][1] += v * w1;
    }
  }
  float* O = isB ? Bp : Ap;
  const float bb0 = isB ? 0.f : b1[t];
  const float bb1 = isB ? 0.f : b1[t + 256];
#pragma unroll
  for (int r = 0; r < 4; ++r) {
    O[(r0 + r) * HDIM + t] = s[r][0] + bb0;
    O[(r0 + r) * HDIM + t + 256] = s[r][1] + bb1;
  }
}

// ---- prep_w2: bf16 W2^T as [kc=k/8 (64)][n (512)] 16B chunks ----
__global__ __launch_bounds__(256) void prep_w2(const float* __restrict__ W2,
                                               unsigned short* __restrict__ W2T) {
  const int o = blockIdx.x * 256 + threadIdx.x;  // 128*256 = 32768 chunks
  const int kc = o >> 9;
  const int n = o & 511;
  unsigned int u[4];
#pragma unroll
  for (int e2 = 0; e2 < 4; ++e2)
    u[e2] = pk2(W2[(kc * 8 + 2 * e2) * HDIM + n], W2[(kc * 8 + 2 * e2 + 1) * HDIM + n]);
  *(uint4*)(W2T + (size_t)o * 8) = make_uint4(u[0], u[1], u[2], u[3]);
}

// ---- main: 64 pair-rows x 512 cols per block; 8 waves, wave = 64x64 tile
// as 2x2 frags of 32x32. K pipelined in 32 steps of 16; af dbuf 1-deep,
// bfr 3-slot distance-2.
__global__ __launch_bounds__(512, 4) void mlp_main(
    const float* __restrict__ Ap, const float* __restrict__ Bp,
    const unsigned short* __restrict__ W2T, const float* __restrict__ b2,
    const float* __restrict__ W3, const float* __restrict__ b3,
    float* __restrict__ out) {
  extern __shared__ char smem[];
  char* sA = smem;  // 64 KB; epilogue reuses as [16 rowpair][256 slot][16B]

  const int tid = threadIdx.x;
  const int wave = tid >> 6;
  const int lane = tid & 63;
  const int cl = lane & 31;   // frag row/col index
  const int hi = lane >> 5;   // k-octet select
  const int r15 = lane & 15;  // row&15 for this lane's af rows (both mt)

  const int m0 = blockIdx.x * 64;
  const int i = m0 >> 9;
  const int j0 = m0 & 511;

  // ---- fill: h1 tile (64 rows x 512 k) -> sA, 4-bit XOR swizzle ----
  {
    const int c = tid & 63;     // 16B chunk (8 k-elems)
    const int rsub = tid >> 6;  // 0..7
    const float4 a0 = *(const float4*)(Ap + i * HDIM + c * 8);
    const float4 a1 = *(const float4*)(Ap + i * HDIM + c * 8 + 4);
#pragma unroll
    for (int it = 0; it < 8; ++it) {
      const int row = it * 8 + rsub;
      const float4 g0 = *(const float4*)(Bp + (size_t)(j0 + row) * HDIM + c * 8);
      const float4 g1 = *(const float4*)(Bp + (size_t)(j0 + row) * HDIM + c * 8 + 4);
      const uint4 v = make_uint4(
          pk2(fmaxf(a0.x + g0.x, 0.f), fmaxf(a0.y + g0.y, 0.f)),
          pk2(fmaxf(a0.z + g0.z, 0.f), fmaxf(a0.w + g0.w, 0.f)),
          pk2(fmaxf(a1.x + g1.x, 0.f), fmaxf(a1.y + g1.y, 0.f)),
          pk2(fmaxf(a1.z + g1.z, 0.f), fmaxf(a1.w + g1.w, 0.f)));
      *(uint4*)(sA + row * 1024 + ((c ^ (row & 15)) << 4)) = v;
    }
  }

  // hoisted epilogue weights (latency hidden under K-loop)
  float w30[2], w31[2], bb[2];
#pragma unroll
  for (int nt = 0; nt < 2; ++nt) {
    const int n = (wave << 6) + (nt << 5) + cl;
    w30[nt] = W3[2 * n];
    w31[nt] = W3[2 * n + 1];
    bb[nt] = b2[n];
  }
  const float bb3_0 = b3[0], bb3_1 = b3[1];

  __syncthreads();

  // ---- pipelined K-loop: s = K/16 step; af from sA, bfr from L2 ----
  f32x16 acc[2][2];
#pragma unroll
  for (int mt = 0; mt < 2; ++mt)
#pragma unroll
    for (int nt = 0; nt < 2; ++nt)
#pragma unroll
      for (int q = 0; q < 16; ++q) acc[mt][nt][q] = 0.f;

  const char* abase0 = sA + cl * 1024;  // mt=1 at +32768
  const char* bbase = (const char*)W2T + (((wave << 6) + cl) << 4) + (hi << 13);

  bf16x8 af[2][2], bfr[3][2];
  {
    const int off = (hi ^ r15) << 4;  // s=0
    af[0][0] = *(const bf16x8*)(abase0 + off);
    af[0][1] = *(const bf16x8*)(abase0 + 32768 + off);
#pragma unroll
    for (int q = 0; q < 2; ++q) {  // s=0,1 -> slots 0,1
      const char* bp = bbase + ((size_t)q << 14);
      bfr[q][0] = *(const bf16x8*)(bp);
      bfr[q][1] = *(const bf16x8*)(bp + (1 << 9));
    }
  }
#pragma unroll
  for (int s = 0; s < 32; ++s) {
    const int cur = s & 1;
    const int nxt = cur ^ 1;
    // bfr prefetch distance 2 into slot (s+2)%3 (consumes s%3 this round)
    if (s < 30) {
      const char* bp = bbase + ((size_t)(s + 2) << 14);
      bfr[(s + 2) % 3][0] = *(const bf16x8*)(bp);
      bfr[(s + 2) % 3][1] = *(const bf16x8*)(bp + (1 << 9));
    }
    // af prefetch s+1
    if (s < 31) {
      const int off = ((((s + 1) << 1) | hi) ^ r15) << 4;
      af[nxt][0] = *(const bf16x8*)(abase0 + off);
      af[nxt][1] = *(const bf16x8*)(abase0 + 32768 + off);
    }
    __builtin_amdgcn_s_setprio(1);
#pragma unroll
    for (int nt = 0; nt < 2; ++nt)
#pragma unroll
      for (int mt = 0; mt < 2; ++mt)
        acc[mt][nt] = __builtin_amdgcn_mfma_f32_32x32x16_bf16(af[cur][mt], bfr[s % 3][nt],
                                                              acc[mt][nt], 0, 0, 0);
    __builtin_amdgcn_s_setprio(0);
  }

  __syncthreads();  // sA reads done; buffer reused below

  // ---- epilogue: h2=relu(acc+b2); p=(h2 row-slice)@W3; LDS reduce ----
  // Buffer layout per mt round: [rowpair rpi:16][slot:256=wave*32+cl][p0,p1,p0',p1']
  for (int mt = 0; mt < 2; ++mt) {
#pragma unroll
    for (int rp = 0; rp < 8; ++rp) {
      const int ra = 2 * rp;  // regs ra, ra+1 -> adjacent rows
      const float h0a = fmaxf(acc[mt][0][ra] + bb[0], 0.f);
      const float h1a = fmaxf(acc[mt][1][ra] + bb[1], 0.f);
      const float h0b = fmaxf(acc[mt][0][ra + 1] + bb[0], 0.f);
      const float h1b = fmaxf(acc[mt][1][ra + 1] + bb[1], 0.f);
      const float4 v = make_float4(h0a * w30[0] + h1a * w30[1], h0a * w31[0] + h1a * w31[1],
                                   h0b * w30[0] + h1b * w30[1], h0b * w31[0] + h1b * w31[1]);
      // row of reg ra: (ra&3) + 8*(ra>>2) + 4*hi ; rpi = row>>1
      const int rpi = ((ra & 3) + 8 * (ra >> 2) + 4 * hi) >> 1;
      *(float4*)(smem + rpi * 4096 + (((wave << 5) + cl) << 4)) = v;
    }
    __syncthreads();
    if (tid < 256) {
      const int rpi = tid >> 4;   // 0..15
      const int sub = tid & 15;   // 16 threads per rowpair
      float4 s = make_float4(0.f, 0.f, 0.f, 0.f);
#pragma unroll
      for (int k = 0; k < 16; ++k) {
        const float4 v = *(const float4*)(smem + rpi * 4096 + ((sub + (k << 4)) << 4));
        s.x += v.x; s.y += v.y; s.z += v.z; s.w += v.w;
      }
#pragma unroll
      for (int d = 1; d < 16; d <<= 1) {
        s.x += __shfl_xor(s.x, d, 64);
        s.y += __shfl_xor(s.y, d, 64);
        s.z += __shfl_xor(s.z, d, 64);
        s.w += __shfl_xor(s.w, d, 64);
      }
      if (sub == 0) {
        const int rg = m0 + (mt << 5) + (rpi << 1);
        *(float4*)(out + rg * 2) =
            make_float4(fmaxf(s.x + bb3_0, 0.f), fmaxf(s.y + bb3_1, 0.f),
                        fmaxf(s.z + bb3_0, 0.f), fmaxf(s.w + bb3_1, 0.f));
      }
    }
    __syncthreads();
  }
}

extern "C" void kernel_launch(void* const* d_in, const int* in_sizes, int n_in,
                              void* d_out, int out_size, void* d_ws, size_t ws_size,
                              hipStream_t stream) {
  const float* V1 = (const float*)d_in[0];
  const float* V2 = (const float*)d_in[1];
  const float* W1 = (const float*)d_in[2];
  const float* b1 = (const float*)d_in[3];
  const float* W2 = (const float*)d_in[4];
  const float* b2 = (const float*)d_in[5];
  const float* W3 = (const float*)d_in[6];
  const float* b3 = (const float*)d_in[7];

  // ws layout: Ap (1MB f32) | Bp (1MB f32) | W2T (512KB bf16 tiled)
  float* Ap = (float*)d_ws;
  float* Bp = Ap + NROW * HDIM;
  unsigned short* W2T = (unsigned short*)(Bp + NROW * HDIM);

  const int smem_bytes = 65536;
  (void)hipFuncSetAttribute((const void*)mlp_main,
                            hipFuncAttributeMaxDynamicSharedMemorySize, smem_bytes);

  prep_ab<<<256, 256, 0, stream>>>(V1, V2, W1, b1, Ap, Bp);
  prep_w2<<<128, 256, 0, stream>>>(W2, W2T);
  mlp_main<<<4096, 512, smem_bytes, stream>>>(Ap, Bp, W2T, b2, W3, b3, (float*)d_out);
}